// Round 7
// baseline (141.445 us; speedup 1.0000x reference)
//
#include <hip/hip_runtime.h>
#include <math.h>

#define N_SURF 40000
#define N_LIG  1024
#define HID    512
#define E_MAX  131072
#define L5     5
#define NBLK   256

// workspace float layout
#define WS_WP     0        // 512*3  : Wp = W_gcn[5] @ W_pos
#define WS_A3     1536     // 9      : W_surf @ Wp
#define WS_BSP    1545     // 3      : b_surf @ Wp
#define WS_BPOUT  1548     // 3      : b_gcn[5]@W_pos + b_pos
#define WS_WHBP   1552     // 64*3   : W_hbias @ Wp
#define WS_AGG    1744     // 1024*3 : sum of surface_pos over in-edges
#define WS_CNT    4816     // 1024   : in-degree
#define WS_ZERO_BEGIN 1744
#define WS_ZERO_COUNT 4096
#define WS_BAR    5840     // 2 uints, memset to 0 by host each call

// grid barrier: 256 blocks, all guaranteed co-resident (1 block/CU).
__device__ __forceinline__ void gridbar(unsigned* cnt) {
    __threadfence();                       // release: flush this block's writes
    __syncthreads();
    if (threadIdx.x == 0) {
        atomicAdd(cnt, 1u);                // device-scope
        while (__hip_atomic_load(cnt, __ATOMIC_ACQUIRE, __HIP_MEMORY_SCOPE_AGENT) < NBLK) {}
    }
    __syncthreads();
    __threadfence();                       // acquire: invalidate stale cache
}

__global__ __launch_bounds__(256) void k_fused(
    const float* __restrict__ Wgcn,  const float* __restrict__ Wpos,
    const float* __restrict__ Wsurf, const float* __restrict__ bsurf,
    const float* __restrict__ bgcn,  const float* __restrict__ bpos,
    const float* __restrict__ Whb,
    const int*   __restrict__ ei,    const float* __restrict__ spos,
    const float* __restrict__ lpos,  const float* __restrict__ tarr,
    const float* __restrict__ Wt1,   const float* __restrict__ bt1,
    const float* __restrict__ Wt2,   const float* __restrict__ bt2,
    const float* __restrict__ Wlig,  const float* __restrict__ blig,
    const float* __restrict__ Wgate, const float* __restrict__ bgate,
    float* __restrict__ ws,          float* __restrict__ out)
{
    __shared__ float s_emb[4][64];
    __shared__ float s_h1[4][256];
    __shared__ float s_ht[4][64];
    __shared__ float s_out[4][4][3];       // [wave][node][3]
    unsigned* bar = (unsigned*)(ws + WS_BAR);
    int t    = threadIdx.x;
    int lane = t & 63;
    int w    = t >> 6;
    int b    = blockIdx.x;                 // 256 blocks
    int i0   = b * 4;                      // 4 ligand nodes per block

    // ========== P0a: Wp rows 2b,2b+1 (waves 0-1) | zero AGG/CNT (waves 2-3) ====
    if (w < 2) {
        int row = b * 2 + w;
        const float* Wg5 = Wgcn + (size_t)L5 * HID * HID + (size_t)row * HID;
        float a0 = 0.f, a1 = 0.f, a2 = 0.f;
        for (int j = lane; j < HID; j += 64) {     // coalesced row read
            float v = Wg5[j];
            a0 += v * Wpos[j * 3 + 0];
            a1 += v * Wpos[j * 3 + 1];
            a2 += v * Wpos[j * 3 + 2];
        }
        for (int m = 32; m; m >>= 1) {
            a0 += __shfl_xor(a0, m);
            a1 += __shfl_xor(a1, m);
            a2 += __shfl_xor(a2, m);
        }
        if (lane == 0) {
            ws[WS_WP + row * 3 + 0] = a0;
            ws[WS_WP + row * 3 + 1] = a1;
            ws[WS_WP + row * 3 + 2] = a2;
        }
    } else {
        int idx = b * 128 + (t - 128);             // 256*128 covers 4096
        if (idx < WS_ZERO_COUNT) ws[WS_ZERO_BEGIN + idx] = 0.f;
    }

    // ========== P0b: time-MLP for this block's 4 nodes (Wp-independent) ========
    {
        float tt = tarr[i0 + w];
        const float coef = -0.29710775f;           // -ln(10000)/31
        float ang = tt * expf(coef * (float)(lane & 31));
        s_emb[w][lane] = (lane < 32) ? sinf(ang) : cosf(ang);
    }
    __syncthreads();
    {   // h1 = gelu(emb @ Wt1 + bt1): thread t owns column t for all 4 nodes
        float bb = bt1[t];
        float acc[4] = {bb, bb, bb, bb};
        #pragma unroll 16
        for (int k = 0; k < 64; ++k) {
            float wv = Wt1[k * 256 + t];
            #pragma unroll
            for (int n = 0; n < 4; ++n) acc[n] += s_emb[n][k] * wv;
        }
        #pragma unroll
        for (int n = 0; n < 4; ++n)
            s_h1[n][t] = 0.5f * acc[n] * (1.f + erff(acc[n] * 0.70710678f));
    }
    __syncthreads();
    {   // ht = h1 @ Wt2 + bt2: wave w -> node w, lane -> output col
        float a0 = 0.f, a1 = 0.f, a2 = 0.f, a3 = 0.f;
        #pragma unroll 16
        for (int k = 0; k < 256; k += 4) {
            a0 += s_h1[w][k + 0] * Wt2[(k + 0) * 64 + lane];
            a1 += s_h1[w][k + 1] * Wt2[(k + 1) * 64 + lane];
            a2 += s_h1[w][k + 2] * Wt2[(k + 2) * 64 + lane];
            a3 += s_h1[w][k + 3] * Wt2[(k + 3) * 64 + lane];
        }
        s_ht[w][lane] = bt2[lane] + ((a0 + a1) + (a2 + a3));
    }
    gridbar(&bar[0]);   // Wp + zeroed AGG/CNT now globally visible; s_ht synced

    // ========== P1a: edge scatter, 2 edges per thread ==========================
    #pragma unroll
    for (int rep = 0; rep < 2; ++rep) {
        int e = rep * (E_MAX / 2) + b * 256 + t;
        int s = ei[e];
        int d = ei[E_MAX + e];
        if (s < N_SURF && d >= N_SURF) {           // surface -> ligand edges only
            int li = d - N_SURF;
            atomicAdd(&ws[WS_AGG + li * 3 + 0], spos[s * 3 + 0]);
            atomicAdd(&ws[WS_AGG + li * 3 + 1], spos[s * 3 + 1]);
            atomicAdd(&ws[WS_AGG + li * 3 + 2], spos[s * 3 + 2]);
            atomicAdd(&ws[WS_CNT + li], 1.0f);
        }
    }
    // ========== P1b: Wp-dependent folds (blocks 0..51, one wave per output) ====
    if (b < 52) {
        int o = b * 4 + w;
        if (o < 207) {
            float acc = 0.f;
            if (o < 9) {
                int a = o / 3, jp = o - a * 3;
                for (int k = lane; k < HID; k += 64)
                    acc += Wsurf[a * HID + k] * ws[WS_WP + k * 3 + jp];
            } else if (o < 12) {
                int jp = o - 9;
                for (int k = lane; k < HID; k += 64)
                    acc += bsurf[k] * ws[WS_WP + k * 3 + jp];
            } else if (o < 15) {
                int jp = o - 12;
                for (int j = lane; j < HID; j += 64)
                    acc += bgcn[L5 * HID + j] * Wpos[j * 3 + jp];
            } else {
                int r = (o - 15) / 3, jp = (o - 15) % 3;
                for (int j = lane; j < HID; j += 64)
                    acc += Whb[r * HID + j] * ws[WS_WP + j * 3 + jp];
            }
            for (int m = 32; m; m >>= 1) acc += __shfl_xor(acc, m);
            if (lane == 0) {
                if (o < 9)        ws[WS_A3 + o] = acc;
                else if (o < 12)  ws[WS_BSP + (o - 9)] = acc;
                else if (o < 15)  ws[WS_BPOUT + (o - 12)] = acc + bpos[o - 12];
                else              ws[WS_WHBP + (o - 15)] = acc;
            }
        }
    }
    // ========== P1c: gate + Wp-fold partials (WS_WP ready after bar0) ==========
    float px[4], py[4], pz[4];
    #pragma unroll
    for (int n = 0; n < 4; ++n) {
        px[n] = lpos[(i0 + n) * 3 + 0];
        py[n] = lpos[(i0 + n) * 3 + 1];
        pz[n] = lpos[(i0 + n) * 3 + 2];
    }
    float a[4][3] = {};
    #pragma unroll
    for (int r = 0; r < 2; ++r) {
        int j = r * 256 + t;
        float bg = bgate[j];
        float g[4] = {bg, bg, bg, bg};
        #pragma unroll 16
        for (int k = 0; k < 64; ++k) {
            float wv = Wgate[k * 512 + j];
            #pragma unroll
            for (int n = 0; n < 4; ++n) g[n] += s_ht[n][k] * wv;
        }
        float wl0 = Wlig[j], wl1 = Wlig[512 + j], wl2 = Wlig[1024 + j], bl = blig[j];
        float wp0 = ws[WS_WP + j * 3 + 0];
        float wp1 = ws[WS_WP + j * 3 + 1];
        float wp2 = ws[WS_WP + j * 3 + 2];
        #pragma unroll
        for (int n = 0; n < 4; ++n) {
            float p  = bl + px[n] * wl0 + py[n] * wl1 + pz[n] * wl2;
            float hl = p * (1.f / (1.f + expf(-g[n])));
            a[n][0] += hl * wp0;
            a[n][1] += hl * wp1;
            a[n][2] += hl * wp2;
        }
    }
    gridbar(&bar[1]);   // AGG/CNT + folds now globally visible

    // ========== P2: Whbp term + reduce + epilogue ==============================
    if (t < 64) {
        float h0  = ws[WS_WHBP + t * 3 + 0];
        float h1v = ws[WS_WHBP + t * 3 + 1];
        float h2  = ws[WS_WHBP + t * 3 + 2];
        #pragma unroll
        for (int n = 0; n < 4; ++n) {
            float ht = s_ht[n][t];
            a[n][0] += ht * h0;
            a[n][1] += ht * h1v;
            a[n][2] += ht * h2;
        }
    }
    #pragma unroll
    for (int n = 0; n < 4; ++n)
        #pragma unroll
        for (int jp = 0; jp < 3; ++jp)
            for (int m = 32; m; m >>= 1) a[n][jp] += __shfl_xor(a[n][jp], m);
    if (lane == 0)
        #pragma unroll
        for (int n = 0; n < 4; ++n)
            #pragma unroll
            for (int jp = 0; jp < 3; ++jp) s_out[w][n][jp] = a[n][jp];
    __syncthreads();
    if (t < 4) {   // thread t -> node i0+t epilogue
        int n = t, i = i0 + n;
        float d  = ws[WS_CNT + i];
        float s1 = 1.f / sqrtf(1.f + d);
        float s2 = 1.f / (1.f + d);
        float c  = s1 * d;
        float ax = s1 * ws[WS_AGG + i * 3 + 0];
        float ay = s1 * ws[WS_AGG + i * 3 + 1];
        float az = s1 * ws[WS_AGG + i * 3 + 2];
        #pragma unroll
        for (int jp = 0; jp < 3; ++jp) {
            float bb = s_out[0][n][jp] + s_out[1][n][jp] + s_out[2][n][jp] + s_out[3][n][jp];
            out[i * 3 + jp] = ax * ws[WS_A3 + 0 + jp] +
                              ay * ws[WS_A3 + 3 + jp] +
                              az * ws[WS_A3 + 6 + jp] +
                              c  * ws[WS_BSP + jp]    +
                              s2 * bb                 +
                              ws[WS_BPOUT + jp];
        }
    }
}

extern "C" void kernel_launch(void* const* d_in, const int* in_sizes, int n_in,
                              void* d_out, int out_size, void* d_ws, size_t ws_size,
                              hipStream_t stream) {
    const float* spos  = (const float*)d_in[0];
    const float* lpos  = (const float*)d_in[1];
    const float* tarr  = (const float*)d_in[2];
    const int*   ei    = (const int*)  d_in[3];
    const float* Wsurf = (const float*)d_in[6];
    const float* bsurf = (const float*)d_in[7];
    const float* Wt1   = (const float*)d_in[8];
    const float* bt1   = (const float*)d_in[9];
    const float* Wt2   = (const float*)d_in[10];
    const float* bt2   = (const float*)d_in[11];
    const float* Wlig  = (const float*)d_in[12];
    const float* blig  = (const float*)d_in[13];
    const float* Wgate = (const float*)d_in[14];
    const float* bgate = (const float*)d_in[15];
    const float* Whb   = (const float*)d_in[16];
    const float* Wgcn  = (const float*)d_in[17];
    const float* bgcn  = (const float*)d_in[18];
    const float* Wpos  = (const float*)d_in[19];
    const float* bpos  = (const float*)d_in[20];
    float* ws  = (float*)d_ws;
    float* out = (float*)d_out;

    // zero the two barrier counters (graph-capturable memset node)
    hipMemsetAsync((char*)d_ws + WS_BAR * sizeof(float), 0, 2 * sizeof(unsigned), stream);

    hipLaunchKernelGGL(k_fused, dim3(NBLK), dim3(256), 0, stream,
                       Wgcn, Wpos, Wsurf, bsurf, bgcn, bpos, Whb,
                       ei, spos, lpos, tarr, Wt1, bt1, Wt2, bt2,
                       Wlig, blig, Wgate, bgate, ws, out);
}

// Round 8
// 56.664 us; speedup vs baseline: 2.4962x; 2.4962x over previous
//
#include <hip/hip_runtime.h>
#include <math.h>

#define N_SURF 40000
#define N_LIG  1024
#define HID    512
#define E_MAX  131072
#define L5     5

// workspace float layout
#define WS_WP     0        // 512*3  : Wp = W_gcn[5] @ W_pos
#define WS_AGG    1744     // 1024*3 : sum of surface_pos over in-edges
#define WS_CNT    4816     // 1024   : in-degree
#define WS_ZERO_BEGIN 1744
#define WS_ZERO_COUNT 4096 // AGG + CNT

// ---- K1: edge scatter (all 512 blocks) + Wp rows (blocks 0..127) ----
__global__ __launch_bounds__(256) void k1(
    const float* __restrict__ Wgcn, const float* __restrict__ Wpos,
    const int*   __restrict__ ei,   const float* __restrict__ spos,
    float* __restrict__ ws)
{
    int t    = threadIdx.x;
    int lane = t & 63;
    int w    = t >> 6;
    int b    = blockIdx.x;

    // edges: fire-and-forget atomics (AGG/CNT pre-zeroed by stream-ordered memset)
    {
        int e = b * 256 + t;                       // 512*256 == E_MAX exactly
        int s = ei[e];
        int d = ei[E_MAX + e];
        if (s < N_SURF && d >= N_SURF) {           // surface -> ligand edges only
            int li = d - N_SURF;
            atomicAdd(&ws[WS_AGG + li * 3 + 0], spos[s * 3 + 0]);
            atomicAdd(&ws[WS_AGG + li * 3 + 1], spos[s * 3 + 1]);
            atomicAdd(&ws[WS_AGG + li * 3 + 2], spos[s * 3 + 2]);
            atomicAdd(&ws[WS_CNT + li], 1.0f);
        }
    }
    // Wp = W_gcn[5] @ W_pos: blocks 0..127, wave w -> row b*4+w
    if (b < 128) {
        int row = b * 4 + w;
        const float* Wg5 = Wgcn + (size_t)L5 * HID * HID + (size_t)row * HID;
        float a0 = 0.f, a1 = 0.f, a2 = 0.f;
        for (int j = lane; j < HID; j += 64) {     // coalesced row read
            float v = Wg5[j];
            a0 += v * Wpos[j * 3 + 0];
            a1 += v * Wpos[j * 3 + 1];
            a2 += v * Wpos[j * 3 + 2];
        }
        for (int m = 32; m; m >>= 1) {
            a0 += __shfl_xor(a0, m);
            a1 += __shfl_xor(a1, m);
            a2 += __shfl_xor(a2, m);
        }
        if (lane == 0) {
            ws[WS_WP + row * 3 + 0] = a0;
            ws[WS_WP + row * 3 + 1] = a1;
            ws[WS_WP + row * 3 + 2] = a2;
        }
    }
}

// ---- K2: per-ligand pipeline, 4 nodes/block; folds computed block-locally ----
__global__ __launch_bounds__(256) void k2(
    const float* __restrict__ Wsurf, const float* __restrict__ bsurf,
    const float* __restrict__ bgcn,  const float* __restrict__ Wpos,
    const float* __restrict__ bpos,
    const float* __restrict__ lpos,  const float* __restrict__ tarr,
    const float* __restrict__ Wt1,   const float* __restrict__ bt1,
    const float* __restrict__ Wt2,   const float* __restrict__ bt2,
    const float* __restrict__ Wlig,  const float* __restrict__ blig,
    const float* __restrict__ Wgate, const float* __restrict__ bgate,
    const float* __restrict__ Whb,
    const float* __restrict__ ws,    float* __restrict__ out)
{
    __shared__ float s_emb[4][64];
    __shared__ float s_h1[4][256];
    __shared__ float s_ht[4][64];
    __shared__ float s_fold[15];           // A3[9], bsp[3], bpout[3]
    __shared__ float s_out[4][4][3];       // [wave][node][3]
    int t    = threadIdx.x;
    int lane = t & 63;
    int w    = t >> 6;
    int b    = blockIdx.x;
    int i0   = b * 4;

    // emb: wave w handles node i0+w
    {
        float tt = tarr[i0 + w];
        const float coef = -0.29710775f;   // -ln(10000)/31
        float ang = tt * expf(coef * (float)(lane & 31));
        s_emb[w][lane] = (lane < 32) ? sinf(ang) : cosf(ang);
    }
    __syncthreads();
    // h1 = gelu(emb @ Wt1 + bt1): thread t owns column t for all 4 nodes
    {
        float bb = bt1[t];
        float acc[4] = {bb, bb, bb, bb};
        #pragma unroll 16
        for (int k = 0; k < 64; ++k) {
            float wv = Wt1[k * 256 + t];
            #pragma unroll
            for (int n = 0; n < 4; ++n) acc[n] += s_emb[n][k] * wv;
        }
        #pragma unroll
        for (int n = 0; n < 4; ++n)
            s_h1[n][t] = 0.5f * acc[n] * (1.f + erff(acc[n] * 0.70710678f));
    }
    __syncthreads();
    // ht = h1 @ Wt2 + bt2: wave w -> node w, lane -> output col
    {
        float a0 = 0.f, a1 = 0.f, a2 = 0.f, a3 = 0.f;
        #pragma unroll 16
        for (int k = 0; k < 256; k += 4) {
            a0 += s_h1[w][k + 0] * Wt2[(k + 0) * 64 + lane];
            a1 += s_h1[w][k + 1] * Wt2[(k + 1) * 64 + lane];
            a2 += s_h1[w][k + 2] * Wt2[(k + 2) * 64 + lane];
            a3 += s_h1[w][k + 3] * Wt2[(k + 3) * 64 + lane];
        }
        s_ht[w][lane] = bt2[lane] + ((a0 + a1) + (a2 + a3));
    }
    // block-local folds: o<9: A3=Wsurf@Wp | o<12: bsp=bsurf@Wp | o<15: bpout
    for (int o = w; o < 15; o += 4) {
        float acc = 0.f;
        if (o < 9) {
            int a = o / 3, jp = o - a * 3;
            for (int k = lane; k < HID; k += 64)
                acc += Wsurf[a * HID + k] * ws[WS_WP + k * 3 + jp];
        } else if (o < 12) {
            int jp = o - 9;
            for (int k = lane; k < HID; k += 64)
                acc += bsurf[k] * ws[WS_WP + k * 3 + jp];
        } else {
            int jp = o - 12;
            for (int j = lane; j < HID; j += 64)
                acc += bgcn[L5 * HID + j] * Wpos[j * 3 + jp];
        }
        for (int m = 32; m; m >>= 1) acc += __shfl_xor(acc, m);
        if (lane == 0) s_fold[o] = acc + ((o >= 12) ? bpos[o - 12] : 0.f);
    }
    __syncthreads();   // s_ht + s_fold ready for all waves

    float px[4], py[4], pz[4];
    #pragma unroll
    for (int n = 0; n < 4; ++n) {
        px[n] = lpos[(i0 + n) * 3 + 0];
        py[n] = lpos[(i0 + n) * 3 + 1];
        pz[n] = lpos[(i0 + n) * 3 + 2];
    }
    float a[4][3] = {};
    // gate + hbias + Wp-fold: thread t owns cols t, t+256 for all 4 nodes
    #pragma unroll
    for (int r = 0; r < 2; ++r) {
        int j = r * 256 + t;
        float bg = bgate[j];
        float g[4]  = {bg, bg, bg, bg};
        float hb[4] = {0.f, 0.f, 0.f, 0.f};
        #pragma unroll 16
        for (int k = 0; k < 64; ++k) {
            float wg = Wgate[k * 512 + j];
            float wh = Whb[k * 512 + j];
            #pragma unroll
            for (int n = 0; n < 4; ++n) {
                float ht = s_ht[n][k];
                g[n]  += ht * wg;
                hb[n] += ht * wh;
            }
        }
        float wl0 = Wlig[j], wl1 = Wlig[512 + j], wl2 = Wlig[1024 + j], bl = blig[j];
        float wp0 = ws[WS_WP + j * 3 + 0];
        float wp1 = ws[WS_WP + j * 3 + 1];
        float wp2 = ws[WS_WP + j * 3 + 2];
        #pragma unroll
        for (int n = 0; n < 4; ++n) {
            float p  = bl + px[n] * wl0 + py[n] * wl1 + pz[n] * wl2;
            float hl = p * (1.f / (1.f + expf(-g[n]))) + hb[n];   // h_lig[j]
            a[n][0] += hl * wp0;
            a[n][1] += hl * wp1;
            a[n][2] += hl * wp2;
        }
    }
    #pragma unroll
    for (int n = 0; n < 4; ++n)
        #pragma unroll
        for (int jp = 0; jp < 3; ++jp)
            for (int m = 32; m; m >>= 1) a[n][jp] += __shfl_xor(a[n][jp], m);
    if (lane == 0)
        #pragma unroll
        for (int n = 0; n < 4; ++n)
            #pragma unroll
            for (int jp = 0; jp < 3; ++jp) s_out[w][n][jp] = a[n][jp];
    __syncthreads();
    if (t < 4) {   // thread t -> node i0+t epilogue
        int n = t, i = i0 + n;
        float d  = ws[WS_CNT + i];
        float s1 = 1.f / sqrtf(1.f + d);
        float s2 = 1.f / (1.f + d);
        float c  = s1 * d;
        float ax = s1 * ws[WS_AGG + i * 3 + 0];
        float ay = s1 * ws[WS_AGG + i * 3 + 1];
        float az = s1 * ws[WS_AGG + i * 3 + 2];
        #pragma unroll
        for (int jp = 0; jp < 3; ++jp) {
            float bb = s_out[0][n][jp] + s_out[1][n][jp] + s_out[2][n][jp] + s_out[3][n][jp];
            out[i * 3 + jp] = ax * s_fold[0 + jp] +
                              ay * s_fold[3 + jp] +
                              az * s_fold[6 + jp] +
                              c  * s_fold[9 + jp] +
                              s2 * bb             +
                              s_fold[12 + jp];
        }
    }
}

extern "C" void kernel_launch(void* const* d_in, const int* in_sizes, int n_in,
                              void* d_out, int out_size, void* d_ws, size_t ws_size,
                              hipStream_t stream) {
    const float* spos  = (const float*)d_in[0];
    const float* lpos  = (const float*)d_in[1];
    const float* tarr  = (const float*)d_in[2];
    const int*   ei    = (const int*)  d_in[3];
    const float* Wsurf = (const float*)d_in[6];
    const float* bsurf = (const float*)d_in[7];
    const float* Wt1   = (const float*)d_in[8];
    const float* bt1   = (const float*)d_in[9];
    const float* Wt2   = (const float*)d_in[10];
    const float* bt2   = (const float*)d_in[11];
    const float* Wlig  = (const float*)d_in[12];
    const float* blig  = (const float*)d_in[13];
    const float* Wgate = (const float*)d_in[14];
    const float* bgate = (const float*)d_in[15];
    const float* Whb   = (const float*)d_in[16];
    const float* Wgcn  = (const float*)d_in[17];
    const float* bgcn  = (const float*)d_in[18];
    const float* Wpos  = (const float*)d_in[19];
    const float* bpos  = (const float*)d_in[20];
    float* ws  = (float*)d_ws;
    float* out = (float*)d_out;

    // zero AGG/CNT (stream-ordered; provides the zero->atomics dependency)
    hipMemsetAsync((char*)d_ws + WS_ZERO_BEGIN * sizeof(float), 0,
                   WS_ZERO_COUNT * sizeof(float), stream);

    hipLaunchKernelGGL(k1, dim3(512), dim3(256), 0, stream, Wgcn, Wpos, ei, spos, ws);
    hipLaunchKernelGGL(k2, dim3(N_LIG / 4), dim3(256), 0, stream,
                       Wsurf, bsurf, bgcn, Wpos, bpos,
                       lpos, tarr, Wt1, bt1, Wt2, bt2,
                       Wlig, blig, Wgate, bgate, Whb, ws, out);
}

// Round 9
// 40.879 us; speedup vs baseline: 3.4601x; 1.3861x over previous
//
#include <hip/hip_runtime.h>
#include <math.h>

#define N_SURF 40000
#define N_LIG  1024
#define HID    512
#define E_MAX  131072
#define L5     5

// workspace float layout
#define WS_WP     0        // 512*3  : Wp = W_gcn[5] @ W_pos
#define WS_A3     1536     // 9      : W_surf @ Wp
#define WS_BSP    1545     // 3      : b_surf @ Wp
#define WS_BPOUT  1548     // 3      : b_gcn[5]@W_pos + b_pos
#define WS_WHBP   1552     // 64*3   : W_hbias @ Wp
#define WS_AGG    1744     // 1024*3 : sum of surface_pos over in-edges
#define WS_CNT    4816     // 1024   : in-degree
#define WS_ZERO_BEGIN 1744
#define WS_ZERO_COUNT 4096 // AGG + CNT

// ---- K1: edge scatter (all 512 blocks) + Wp rows (blocks 0..127) ----
__global__ __launch_bounds__(256) void k1(
    const float* __restrict__ Wgcn, const float* __restrict__ Wpos,
    const int*   __restrict__ ei,   const float* __restrict__ spos,
    float* __restrict__ ws)
{
    int t    = threadIdx.x;
    int lane = t & 63;
    int w    = t >> 6;
    int b    = blockIdx.x;

    // edges: AGG/CNT pre-zeroed by the stream-ordered memset
    {
        int e = b * 256 + t;                       // 512*256 == E_MAX exactly
        int s = ei[e];
        int d = ei[E_MAX + e];
        if (s < N_SURF && d >= N_SURF) {           // surface -> ligand edges only
            int li = d - N_SURF;
            atomicAdd(&ws[WS_AGG + li * 3 + 0], spos[s * 3 + 0]);
            atomicAdd(&ws[WS_AGG + li * 3 + 1], spos[s * 3 + 1]);
            atomicAdd(&ws[WS_AGG + li * 3 + 2], spos[s * 3 + 2]);
            atomicAdd(&ws[WS_CNT + li], 1.0f);
        }
    }
    // Wp = W_gcn[5] @ W_pos: blocks 0..127, wave w -> row b*4+w
    if (b < 128) {
        int row = b * 4 + w;
        const float* Wg5 = Wgcn + (size_t)L5 * HID * HID + (size_t)row * HID;
        float a0 = 0.f, a1 = 0.f, a2 = 0.f;
        for (int j = lane; j < HID; j += 64) {     // coalesced row read
            float v = Wg5[j];
            a0 += v * Wpos[j * 3 + 0];
            a1 += v * Wpos[j * 3 + 1];
            a2 += v * Wpos[j * 3 + 2];
        }
        for (int m = 32; m; m >>= 1) {
            a0 += __shfl_xor(a0, m);
            a1 += __shfl_xor(a1, m);
            a2 += __shfl_xor(a2, m);
        }
        if (lane == 0) {
            ws[WS_WP + row * 3 + 0] = a0;
            ws[WS_WP + row * 3 + 1] = a1;
            ws[WS_WP + row * 3 + 2] = a2;
        }
    }
}

// ---- K1b: Wp-dependent folds, one wave per output (52 blocks) ----
// o<9: A3 | o<12: bsp | o<15: bpout | o<207: Whbp[o-15]
__global__ __launch_bounds__(256) void k1b(
    const float* __restrict__ Wsurf, const float* __restrict__ bsurf,
    const float* __restrict__ bgcn,  const float* __restrict__ Wpos,
    const float* __restrict__ bpos,  const float* __restrict__ Whb,
    float* __restrict__ ws)
{
    int lane = threadIdx.x & 63;
    int w    = threadIdx.x >> 6;
    int o    = blockIdx.x * 4 + w;
    if (o >= 207) return;
    float acc = 0.f;
    if (o < 9) {
        int a = o / 3, jp = o - a * 3;
        for (int k = lane; k < HID; k += 64)
            acc += Wsurf[a * HID + k] * ws[WS_WP + k * 3 + jp];
    } else if (o < 12) {
        int jp = o - 9;
        for (int k = lane; k < HID; k += 64)
            acc += bsurf[k] * ws[WS_WP + k * 3 + jp];
    } else if (o < 15) {
        int jp = o - 12;
        for (int j = lane; j < HID; j += 64)
            acc += bgcn[L5 * HID + j] * Wpos[j * 3 + jp];
    } else {
        int r = (o - 15) / 3, jp = (o - 15) % 3;
        for (int j = lane; j < HID; j += 64)
            acc += Whb[r * HID + j] * ws[WS_WP + j * 3 + jp];
    }
    for (int m = 32; m; m >>= 1) acc += __shfl_xor(acc, m);
    if (lane == 0) {
        if (o < 9)        ws[WS_A3 + o] = acc;
        else if (o < 12)  ws[WS_BSP + (o - 9)] = acc;
        else if (o < 15)  ws[WS_BPOUT + (o - 12)] = acc + bpos[o - 12];
        else              ws[WS_WHBP + (o - 15)] = acc;
    }
}

// ---- K2: per-ligand pipeline, 2 nodes per block (512 blocks, 2 blk/CU) ----
__global__ __launch_bounds__(256) void k2(
    const float* __restrict__ lpos,  const float* __restrict__ tarr,
    const float* __restrict__ Wt1,   const float* __restrict__ bt1,
    const float* __restrict__ Wt2,   const float* __restrict__ bt2,
    const float* __restrict__ Wlig,  const float* __restrict__ blig,
    const float* __restrict__ Wgate, const float* __restrict__ bgate,
    const float* __restrict__ ws,    float* __restrict__ out)
{
    __shared__ float s_emb[2][64];
    __shared__ float s_h1[2][256];
    __shared__ float s_red[2][2][64];      // [k-half][node][col]
    __shared__ float s_ht[2][64];
    __shared__ float s_out[4][2][3];       // [wave][node][3]
    int t    = threadIdx.x;
    int lane = t & 63;
    int w    = t >> 6;
    int b    = blockIdx.x;
    int i0   = b * 2;

    // emb: waves 0,1 -> node w
    if (w < 2) {
        float tt = tarr[i0 + w];
        const float coef = -0.29710775f;   // -ln(10000)/31
        float ang = tt * expf(coef * (float)(lane & 31));
        s_emb[w][lane] = (lane < 32) ? sinf(ang) : cosf(ang);
    }
    __syncthreads();
    // h1 = gelu(emb @ Wt1 + bt1): thread t owns column t for both nodes
    {
        float bb = bt1[t];
        float acc0 = bb, acc1 = bb;
        #pragma unroll 16
        for (int k = 0; k < 64; ++k) {
            float wv = Wt1[k * 256 + t];
            acc0 += s_emb[0][k] * wv;
            acc1 += s_emb[1][k] * wv;
        }
        s_h1[0][t] = 0.5f * acc0 * (1.f + erff(acc0 * 0.70710678f));
        s_h1[1][t] = 0.5f * acc1 * (1.f + erff(acc1 * 0.70710678f));
    }
    __syncthreads();
    // ht partials: wave w -> node (w&1), k-half (w>>1)*128
    {
        int n  = w & 1;
        int k0 = (w >> 1) * 128;
        float a0 = 0.f, a1 = 0.f, a2 = 0.f, a3 = 0.f;
        #pragma unroll 16
        for (int kk = 0; kk < 128; kk += 4) {
            int k = k0 + kk;
            a0 += s_h1[n][k + 0] * Wt2[(k + 0) * 64 + lane];
            a1 += s_h1[n][k + 1] * Wt2[(k + 1) * 64 + lane];
            a2 += s_h1[n][k + 2] * Wt2[(k + 2) * 64 + lane];
            a3 += s_h1[n][k + 3] * Wt2[(k + 3) * 64 + lane];
        }
        s_red[w >> 1][n][lane] = (a0 + a1) + (a2 + a3);
    }
    __syncthreads();
    if (t < 128) {
        int n = t >> 6;
        s_ht[n][lane] = bt2[lane] + s_red[0][n][lane] + s_red[1][n][lane];
    }
    __syncthreads();

    float px[2], py[2], pz[2];
    #pragma unroll
    for (int n = 0; n < 2; ++n) {
        px[n] = lpos[(i0 + n) * 3 + 0];
        py[n] = lpos[(i0 + n) * 3 + 1];
        pz[n] = lpos[(i0 + n) * 3 + 2];
    }
    float a[2][3] = {};
    // gate + Wp-fold: thread t owns cols t, t+256 (hbias folded via Whbp)
    #pragma unroll
    for (int r = 0; r < 2; ++r) {
        int j = r * 256 + t;
        float bg = bgate[j];
        float g0 = bg, g1 = bg;
        #pragma unroll 16
        for (int k = 0; k < 64; ++k) {
            float wg = Wgate[k * 512 + j];
            g0 += s_ht[0][k] * wg;
            g1 += s_ht[1][k] * wg;
        }
        float wl0 = Wlig[j], wl1 = Wlig[512 + j], wl2 = Wlig[1024 + j], bl = blig[j];
        float wp0 = ws[WS_WP + j * 3 + 0];
        float wp1 = ws[WS_WP + j * 3 + 1];
        float wp2 = ws[WS_WP + j * 3 + 2];
        float g[2] = {g0, g1};
        #pragma unroll
        for (int n = 0; n < 2; ++n) {
            float p  = bl + px[n] * wl0 + py[n] * wl1 + pz[n] * wl2;
            float hl = p * (1.f / (1.f + expf(-g[n])));
            a[n][0] += hl * wp0;
            a[n][1] += hl * wp1;
            a[n][2] += hl * wp2;
        }
    }
    // + h_time @ Whbp (64x3 precomputed)
    if (t < 64) {
        float h0  = ws[WS_WHBP + t * 3 + 0];
        float h1v = ws[WS_WHBP + t * 3 + 1];
        float h2  = ws[WS_WHBP + t * 3 + 2];
        #pragma unroll
        for (int n = 0; n < 2; ++n) {
            float ht = s_ht[n][t];
            a[n][0] += ht * h0;
            a[n][1] += ht * h1v;
            a[n][2] += ht * h2;
        }
    }
    #pragma unroll
    for (int n = 0; n < 2; ++n)
        #pragma unroll
        for (int jp = 0; jp < 3; ++jp)
            for (int m = 32; m; m >>= 1) a[n][jp] += __shfl_xor(a[n][jp], m);
    if (lane == 0)
        #pragma unroll
        for (int n = 0; n < 2; ++n)
            #pragma unroll
            for (int jp = 0; jp < 3; ++jp) s_out[w][n][jp] = a[n][jp];
    __syncthreads();
    if (t < 2) {   // thread t -> node i0+t epilogue
        int n = t, i = i0 + n;
        float d  = ws[WS_CNT + i];
        float s1 = 1.f / sqrtf(1.f + d);
        float s2 = 1.f / (1.f + d);
        float c  = s1 * d;
        float ax = s1 * ws[WS_AGG + i * 3 + 0];
        float ay = s1 * ws[WS_AGG + i * 3 + 1];
        float az = s1 * ws[WS_AGG + i * 3 + 2];
        #pragma unroll
        for (int jp = 0; jp < 3; ++jp) {
            float bb = s_out[0][n][jp] + s_out[1][n][jp] + s_out[2][n][jp] + s_out[3][n][jp];
            out[i * 3 + jp] = ax * ws[WS_A3 + 0 + jp] +
                              ay * ws[WS_A3 + 3 + jp] +
                              az * ws[WS_A3 + 6 + jp] +
                              c  * ws[WS_BSP + jp]    +
                              s2 * bb                 +
                              ws[WS_BPOUT + jp];
        }
    }
}

extern "C" void kernel_launch(void* const* d_in, const int* in_sizes, int n_in,
                              void* d_out, int out_size, void* d_ws, size_t ws_size,
                              hipStream_t stream) {
    const float* spos  = (const float*)d_in[0];
    const float* lpos  = (const float*)d_in[1];
    const float* tarr  = (const float*)d_in[2];
    const int*   ei    = (const int*)  d_in[3];
    const float* Wsurf = (const float*)d_in[6];
    const float* bsurf = (const float*)d_in[7];
    const float* Wt1   = (const float*)d_in[8];
    const float* bt1   = (const float*)d_in[9];
    const float* Wt2   = (const float*)d_in[10];
    const float* bt2   = (const float*)d_in[11];
    const float* Wlig  = (const float*)d_in[12];
    const float* blig  = (const float*)d_in[13];
    const float* Wgate = (const float*)d_in[14];
    const float* bgate = (const float*)d_in[15];
    const float* Whb   = (const float*)d_in[16];
    const float* Wgcn  = (const float*)d_in[17];
    const float* bgcn  = (const float*)d_in[18];
    const float* Wpos  = (const float*)d_in[19];
    const float* bpos  = (const float*)d_in[20];
    float* ws  = (float*)d_ws;
    float* out = (float*)d_out;

    // zero AGG/CNT (stream-ordered; provides the zero->atomics dependency)
    hipMemsetAsync((char*)d_ws + WS_ZERO_BEGIN * sizeof(float), 0,
                   WS_ZERO_COUNT * sizeof(float), stream);

    hipLaunchKernelGGL(k1,  dim3(512), dim3(256), 0, stream, Wgcn, Wpos, ei, spos, ws);
    hipLaunchKernelGGL(k1b, dim3(52),  dim3(256), 0, stream,
                       Wsurf, bsurf, bgcn, Wpos, bpos, Whb, ws);
    hipLaunchKernelGGL(k2,  dim3(N_LIG / 2), dim3(256), 0, stream,
                       lpos, tarr, Wt1, bt1, Wt2, bt2,
                       Wlig, blig, Wgate, bgate, ws, out);
}